// Round 15
// baseline (4668.599 us; speedup 1.0000x reference)
//
#include <hip/hip_runtime.h>
#include <cstddef>

// Basis-propagation; iteration in PURE bf16, post-fields/H/Y in bf16 hi/lo.
// State S[pos][n][c] channel-minor, guard bands; invalid taps = zero-weight.
// R15: roles 1-3 process TWO n-tiles serially per block (same position /
// m-stripe): second pass's weight reads (W4P/W4Q slices) hit the same XCD's
// L2 -> W4 beyond-L2 traffic halves. mloop/epilogues untouched; grids
// iter 1351 / post 714. Bit-identical results. Role0 patch = R14.

typedef unsigned short ushort_t;
typedef __attribute__((ext_vector_type(8))) short bf8_t;   // 8 bf16
typedef __attribute__((ext_vector_type(4))) float f4_t;

#define MFMA16 __builtin_amdgcn_mfma_f32_16x16x32_bf16

#define NBn 832
#define NITER 50
#define GPL 5218304u       // u1/G plane size (196*26624)

// state plane geometry (elems), with guards:
#define SELG 13125632u
#define R1G 399360
#define R2G 6043648
#define R3G 9877504
#define R4G 12912640

// packed weights (elems; each matrix = [hi plane][lo plane])
#define W2F_OFF 0u
#define W2B_OFF 36864u
#define W3F_OFF 73728u
#define W3B_OFF 147456u
#define W4P_OFF 221184u
#define W4Q_OFF 1826816u
#define W2PL 18432u
#define W3PL 36864u
#define W4PL 802816u
#define ZOFF 3432448u
#define WPTOT2 3435008u

__device__ __forceinline__ void bsplit(float v, ushort_t& h, ushort_t& lo) {
  union { float f; unsigned u; } a; a.f = v;
  unsigned uh = (a.u + 0x7fffu + ((a.u >> 16) & 1u)) & 0xffff0000u;
  h = (ushort_t)(uh >> 16);
  union { unsigned u; float f; } b; b.u = uh;
  float r = v - b.f;
  union { float f; unsigned u; } c; c.f = r;
  lo = (ushort_t)((c.u + 0x7fffu + ((c.u >> 16) & 1u)) >> 16);
}

__device__ __forceinline__ ushort_t bround(float v) {
  union { float f; unsigned u; } a; a.f = v;
  return (ushort_t)((a.u + 0x7fffu + ((a.u >> 16) & 1u)) >> 16);
}

__device__ __forceinline__ float b2f(ushort_t h) {
  union { unsigned u; float f; } a; a.u = ((unsigned)h) << 16;
  return a.f;
}

__device__ __forceinline__ float bjoin(ushort_t h, ushort_t l) {
  return b2f(h) + b2f(l);
}

// bijective chunked XCD swizzle
__device__ __forceinline__ int xswz(int lin, int nwg) {
  int xcd = lin & 7, o = lin >> 3;
  int q = nwg >> 3, r = nwg & 7;
  return (xcd < r) ? (xcd * (q + 1) + o) : (r * (q + 1) + (xcd - r) * q + o);
}

__global__ void k_fill0(float* p, unsigned n) {
  for (unsigned i = blockIdx.x * blockDim.x + threadIdx.x; i < n;
       i += gridDim.x * blockDim.x)
    p[i] = 0.f;
}

__global__ void k_pack2(const float* __restrict__ w2, ushort_t* __restrict__ WP) {
  int idx = blockIdx.x * blockDim.x + threadIdx.x;
  if (idx >= 18432) return;
  int co = idx / 288, rem = idx % 288, ci = rem / 9, t = rem % 9;
  ushort_t h, l; bsplit(w2[idx], h, l);
  unsigned f = W2F_OFF + t * 2048 + co * 32 + ci;
  unsigned b = W2B_OFF + t * 2048 + ci * 64 + co;
  WP[f] = h; WP[f + W2PL] = l;
  WP[b] = h; WP[b + W2PL] = l;
}

__global__ void k_pack3(const float* __restrict__ w3, ushort_t* __restrict__ WP) {
  int idx = blockIdx.x * blockDim.x + threadIdx.x;
  if (idx >= 36864) return;
  int co = idx / 576, rem = idx % 576, ci = rem / 9, t = rem % 9;
  ushort_t h, l; bsplit(w3[idx], h, l);
  unsigned f = W3F_OFF + t * 4096 + co * 64 + ci;
  unsigned b = W3B_OFF + t * 4096 + ci * 64 + co;
  WP[f] = h; WP[f + W3PL] = l;
  WP[b] = h; WP[b + W3PL] = l;
}

__global__ void k_pack4(const float* __restrict__ w4, ushort_t* __restrict__ WP) {
  int idx = blockIdx.x * blockDim.x + threadIdx.x;
  if (idx >= 802816) return;
  int o = idx / 3136, kk = idx % 3136, c = kk / 49, p = kk % 49;
  ushort_t h, l; bsplit(w4[idx], h, l);
  unsigned a = W4P_OFF + p * 16384 + c * 256 + o;
  unsigned b = W4Q_OFF + o * 3136 + p * 64 + c;
  WP[a] = h; WP[a + W4PL] = l;
  WP[b] = h; WP[b + W4PL] = l;
}

// u1[q][n][c]: conv1 of basis vector n (n==784 -> b1, pads 0), split bf16
__global__ void k_u1b(ushort_t* __restrict__ G, const float* __restrict__ w1,
                      const float* __restrict__ b1) {
  unsigned idx = blockIdx.x * blockDim.x + threadIdx.x;
  if (idx >= GPL) return;
  int q = idx / 26624, rem = idx % 26624, n = rem / 32, c = rem % 32;
  int oy = q / 14, ox = q % 14;
  float v = 0.f;
  if (n < 784) {
    int py = n / 28, px = n % 28;
    int ky = py - (2 * oy - 1), kx = px - (2 * ox - 1);
    if (ky >= 0 && ky < 3 && kx >= 0 && kx < 3) v = w1[c * 9 + ky * 3 + kx];
  } else if (n == 784) {
    v = b1[c];
  }
  ushort_t h, l; bsplit(v, h, l);
  G[idx] = h; G[idx + GPL] = l;
}

// P1 = 0.5*s1_final - u1  (hi/lo into Pb)
__global__ void k_p1(ushort_t* __restrict__ D, const ushort_t* __restrict__ S,
                     const ushort_t* __restrict__ G) {
  unsigned g8 = (blockIdx.x * blockDim.x + threadIdx.x) * 8;
  if (g8 >= GPL) return;
  size_t off = (size_t)R1G + g8;
  bf8_t oh = *(const bf8_t*)&S[off];
  bf8_t gh = *(const bf8_t*)&G[g8], gl = *(const bf8_t*)&G[g8 + GPL];
  bf8_t rh, rl;
#pragma unroll
  for (int e = 0; e < 8; ++e) {
    float v = 0.5f * b2f((ushort_t)oh[e]) -
              bjoin((ushort_t)gh[e], (ushort_t)gl[e]);
    ushort_t h, l; bsplit(v, h, l);
    rh[e] = (short)h; rl[e] = (short)l;
  }
  *(bf8_t*)&D[off] = rh;
  *(bf8_t*)&D[off + SELG] = rl;
}

// ---- chunk descriptors (roles 1-3) ----
struct Ent { unsigned eh, el; int b; int ars, brs; };

__device__ __forceinline__ Ent entry(int role, int e, int p, int mt, int post) {
  Ent E;
  if (role == 3) {
    E.eh = W4Q_OFF + ((unsigned)mt * 64u) * 3136u + (unsigned)e * 32u;
    E.el = E.eh + W4PL;
    E.b = R3G + (e >> 1) * 53248 + (e & 1) * 32;
    E.ars = 3136; E.brs = 64;
  } else if (role == 2) {
    int y = p / 7, x = p % 7;
    if (e < 18) {
      int t = e >> 1, sub = e & 1, ky = t / 3, kx = t % 3;
      int iy = y - 1 + ky, ix = x - 1 + kx;
      bool v = (iy >= 0 && iy < 7 && ix >= 0 && ix < 7);
      E.eh = v ? (W3F_OFF + t * 4096u + sub * 32u) : ZOFF;
      E.el = v ? (E.eh + W3PL) : ZOFF;
      E.b = R2G + (iy * 7 + ix) * 53248 + sub * 32;
      E.ars = v ? 64 : 32; E.brs = 64;
    } else {
      int s = e - 18;
      E.eh = W4P_OFF + (unsigned)p * 16384u + s * 32u;
      E.el = E.eh + W4PL;
      E.b = R4G + s * 32;
      E.ars = 256; E.brs = 256;
    }
  } else {  // role 1
    int y = p / 7, x = p % 7;
    if (e < 9) {
      int ky = e / 3, kx = e % 3;
      int iy = 2 * y - 1 + ky, ix = 2 * x - 1 + kx;
      bool v = (iy >= 0 && iy < 14 && ix >= 0 && ix < 14);
      E.eh = v ? (W2F_OFF + e * 2048u) : ZOFF;
      E.el = v ? (E.eh + W2PL) : ZOFF;
      E.b = R1G + (iy * 14 + ix) * 26624;
      E.ars = 32; E.brs = 32;
    } else if (e < 27 && !post) {
      int u = e - 9, t = u >> 1, sub = u & 1, ky = t / 3, kx = t % 3;
      int ty = y + 1 - ky, tx = x + 1 - kx;
      bool v = (ty >= 0 && ty < 7 && tx >= 0 && tx < 7);
      E.eh = v ? (W3B_OFF + t * 4096u + sub * 32u) : ZOFF;
      E.el = v ? (E.eh + W3PL) : ZOFF;
      E.b = R3G + (ty * 7 + tx) * 53248 + sub * 32;
      E.ars = v ? 64 : 32; E.brs = 64;
    } else {
      E.eh = ZOFF; E.el = ZOFF; E.b = R4G; E.ars = 32; E.brs = 256;
    }
  }
  return E;
}

__device__ __forceinline__ Ent entryg(int role, int e, int p, int mt, int post,
                                      int elim) {
  if (e >= elim) {
    Ent E; E.eh = ZOFF; E.el = ZOFF; E.b = R4G; E.ars = 32; E.brs = 256;
    return E;
  }
  return entry(role, e, p, mt, post);
}

template <int APL, int MI>
__device__ __forceinline__ void loadA(bf8_t (&A0)[MI][APL], bf8_t (&A1)[MI][APL],
                                      int role, int e0, int p, int mt, int post,
                                      int elim, int mhalf, int lm, int koff,
                                      const ushort_t* __restrict__ WP) {
  Ent E0 = entryg(role, e0, p, mt, post, elim);
  Ent E1 = entryg(role, e0 + 1, p, mt, post, elim);
#pragma unroll
  for (int mi = 0; mi < MI; ++mi) {
    int mo0 = (mhalf + mi * 16 + lm) * E0.ars + koff;
    int mo1 = (mhalf + mi * 16 + lm) * E1.ars + koff;
    A0[mi][0] = *(const bf8_t*)(WP + E0.eh + mo0);
    A1[mi][0] = *(const bf8_t*)(WP + E1.eh + mo1);
    if (APL == 2) {
      A0[mi][APL - 1] = *(const bf8_t*)(WP + E0.el + mo0);
      A1[mi][APL - 1] = *(const bf8_t*)(WP + E1.el + mo1);
    }
  }
}

__device__ __forceinline__ void loadB(bf8_t& s0, bf8_t& s1, int role, int e0,
                                      int p, int mt, int post, int elim, int n0,
                                      int sn, int sc,
                                      const ushort_t* __restrict__ S) {
  Ent E0 = entryg(role, e0, p, mt, post, elim);
  Ent E1 = entryg(role, e0 + 1, p, mt, post, elim);
  s0 = *(const bf8_t*)(S + E0.b + (n0 + sn) * E0.brs + sc);
  s1 = *(const bf8_t*)(S + E1.b + (n0 + sn) * E1.brs + sc);
}

template <int APL, int MI, int NJ>
__device__ __forceinline__ void mfmaset(const bf8_t (&A0)[MI][APL],
                                        const bf8_t (&A1)[MI][APL],
                                        const ushort_t* __restrict__ Bb, int nhalf,
                                        int lm, int koff, f4_t (&acc)[MI][NJ]) {
#pragma unroll
  for (int nj = 0; nj < NJ; ++nj) {
    int lo = (nhalf + nj * 16 + lm) * 40 + koff;
    bf8_t b0 = *(const bf8_t*)&Bb[lo];
    bf8_t b1 = *(const bf8_t*)&Bb[2560 + lo];
#pragma unroll
    for (int mi = 0; mi < MI; ++mi)
#pragma unroll
      for (int pl = 0; pl < APL; ++pl) {
        acc[mi][nj] = MFMA16(A0[mi][pl], b0, acc[mi][nj], 0, 0, 0);
        acc[mi][nj] = MFMA16(A1[mi][pl], b1, acc[mi][nj], 0, 0, 0);
      }
  }
}

// depth-4 B staging pipeline (roles 1-3), as in R12
template <int APL, int MI, int NJ>
__device__ __forceinline__ void mloop(int role, int post, int p, int mt, int n0,
                                      int NC2, int mhalf, int nhalf,
                                      const ushort_t* __restrict__ S,
                                      const ushort_t* __restrict__ WP,
                                      ushort_t* __restrict__ SB,
                                      f4_t (&acc)[MI][NJ]) {
  const int tid = threadIdx.x, l = tid & 63;
  const int lm = l & 15, koff = (l >> 4) * 8;
  const int sn = tid >> 2, sc = (tid & 3) * 8;
  const int elim = 2 * NC2;
  bf8_t bs0[4], bs1[4];
#pragma unroll
  for (int q = 0; q < 4; ++q)
    loadB(bs0[q], bs1[q], role, 2 * q, p, mt, post, elim, n0, sn, sc, S);
  bf8_t aE0[MI][APL], aE1[MI][APL], aO0[MI][APL], aO1[MI][APL];
  loadA<APL, MI>(aE0, aE1, role, 0, p, mt, post, elim, mhalf, lm, koff, WP);
  loadA<APL, MI>(aO0, aO1, role, 2, p, mt, post, elim, mhalf, lm, koff, WP);
  {
    int wb = sn * 40 + sc;
    *(bf8_t*)&SB[wb] = bs0[0];
    *(bf8_t*)&SB[wb + 2560] = bs1[0];
  }
  __syncthreads();
  const int ntrip = (NC2 + 3) >> 2;
  for (int t4 = 0; t4 < ntrip; ++t4) {
    int j4 = t4 * 4;
#pragma unroll
    for (int pp = 0; pp < 4; ++pp) {
      int jj = j4 + pp;
      loadB(bs0[pp], bs1[pp], role, 2 * (jj + 4), p, mt, post, elim, n0, sn, sc, S);
      const ushort_t* Bb = SB + (pp & 1) * 5120;
      if ((pp & 1) == 0) {
        mfmaset<APL, MI, NJ>(aE0, aE1, Bb, nhalf, lm, koff, acc);
        loadA<APL, MI>(aE0, aE1, role, 2 * (jj + 2), p, mt, post, elim, mhalf, lm,
                       koff, WP);
      } else {
        mfmaset<APL, MI, NJ>(aO0, aO1, Bb, nhalf, lm, koff, acc);
        loadA<APL, MI>(aO0, aO1, role, 2 * (jj + 2), p, mt, post, elim, mhalf, lm,
                       koff, WP);
      }
      {
        int wb = sn * 40 + sc;
        ushort_t* Wb = SB + ((pp + 1) & 1) * 5120;
        *(bf8_t*)&Wb[wb] = bs0[(pp + 1) & 3];
        *(bf8_t*)&Wb[wb + 2560] = bs1[(pp + 1) & 3];
      }
      __syncthreads();
    }
  }
}

// mega kernel: iter blocks [role3 28][role2 343][role1 343][role0-patch 637]
// post blocks [role3 28][role2 343][role1 343]
// roles 1-3: TWO serial 64-col n-tiles per block (weight slice L2 reuse)
template <int POST>
__global__ __launch_bounds__(256) void k_mega(
    const ushort_t* __restrict__ S, ushort_t* __restrict__ D,
    const ushort_t* __restrict__ G, const ushort_t* __restrict__ WP,
    const float* __restrict__ b2, const float* __restrict__ b3,
    const float* __restrict__ b4) {
  __shared__ __align__(16) ushort_t SB[20480];
  float* Lt = (float*)SB;
  const int tid = threadIdx.x, l = tid & 63, w = tid >> 6;
  const int lm = l & 15, lk = l >> 4;
  int b = blockIdx.x;
  int role, rb, ntp, pq;
  if (b < 28) { role = 3; rb = xswz(b, 28); ntp = rb >> 2; pq = rb & 3; }
  else if (b < 371) { role = 2; rb = xswz(b - 28, 343); ntp = rb / 49; pq = rb % 49; }
  else if (b < 714) { role = 1; rb = xswz(b - 371, 343); ntp = rb / 49; pq = rb % 49; }
  else { role = 0; rb = xswz(b - 714, 637); ntp = rb / 49; pq = rb % 49; }

  if (role == 0) {
    int n0 = ntp * 64;
    // 2x2 patch at (Y,X) on the 7x7 patch grid; positions (2Y+py, 2X+px).
    const int Y = pq / 7, X = pq % 7;
    const int sn = tid >> 2, sc = (tid & 3) * 8;
    const int koff = lk * 8;
    bf8_t breg[8];
#pragma unroll
    for (int e = 0; e < 8; ++e) {
      int t2 = e >> 1, dy = t2 >> 1, dx = t2 & 1, sub = e & 1;
      bool tv = (Y + dy < 7) && (X + dx < 7);
      int bbase = tv ? (R2G + ((Y + dy) * 7 + (X + dx)) * 53248 + sub * 32) : R4G;
      breg[e] = *(const bf8_t*)(S + bbase + (n0 + sn) * 64 + sc);
    }
    {
      int wb = sn * 40 + sc;
#pragma unroll
      for (int e = 0; e < 8; ++e) *(bf8_t*)&SB[e * 2560 + wb] = breg[e];
    }
    __syncthreads();
    f4_t acc[4][2] = {};
    const int nloc = w * 16 + lm;
#pragma unroll
    for (int e = 0; e < 8; ++e) {
      int t2 = e >> 1, dy = t2 >> 1, dx = t2 & 1, sub = e & 1;
      bool tv = (Y + dy < 7) && (X + dx < 7);
      bf8_t bfr = *(const bf8_t*)&SB[e * 2560 + nloc * 40 + koff];
#pragma unroll
      for (int py = 0; py < 2; ++py) {
#pragma unroll
        for (int px = 0; px < 2; ++px) {
          const int ky = py + 1 - 2 * dy, kx = px + 1 - 2 * dx;
          if (ky >= 0 && kx >= 0) {
            unsigned abase = tv ? (W2B_OFF + (unsigned)(ky * 3 + kx) * 2048u +
                                   (unsigned)sub * 32u)
                                : ZOFF;
            const int pos = py * 2 + px;
#pragma unroll
            for (int mi = 0; mi < 2; ++mi) {
              bf8_t afr = *(const bf8_t*)(WP + abase + (mi * 16 + lm) * 64 + koff);
              acc[pos][mi] = MFMA16(afr, bfr, acc[pos][mi], 0, 0, 0);
            }
          }
        }
      }
    }
#pragma unroll
    for (int pos = 0; pos < 4; ++pos) {
      __syncthreads();
#pragma unroll
      for (int mi = 0; mi < 2; ++mi)
#pragma unroll
        for (int r = 0; r < 4; ++r)
          Lt[(w * 16 + lm) * 33 + mi * 16 + lk * 4 + r] = acc[pos][mi][r];
      __syncthreads();
      int q = (2 * Y + (pos >> 1)) * 14 + 2 * X + (pos & 1);
      int nl = tid >> 2, cq = (tid & 3) * 8;
      int n = n0 + nl;
      size_t off = (size_t)R1G + (size_t)q * 26624 + (size_t)n * 32 + cq;
      size_t goff = (size_t)q * 26624 + (size_t)n * 32 + cq;
      bf8_t oh = *(const bf8_t*)&S[off];
      bf8_t gh = *(const bf8_t*)&G[goff], gl = *(const bf8_t*)&G[goff + GPL];
      const float* lp = Lt + nl * 33 + cq;
      bf8_t rh;
#pragma unroll
      for (int e = 0; e < 8; ++e) {
        float old = b2f((ushort_t)oh[e]);
        float u = bjoin((ushort_t)gh[e], (ushort_t)gl[e]);
        rh[e] = (short)bround(0.5f * old + 0.5f * (lp[e] + u));
      }
      *(bf8_t*)&D[off] = rh;
    }
  } else {
    int NC2 = (role == 3) ? 49 : (role == 2) ? (POST ? 9 : 13) : (POST ? 5 : 14);
#pragma unroll
    for (int tp = 0; tp < 2; ++tp) {
      int nt = ntp * 2 + tp;
      if (nt >= 13) break;
      int n0 = nt * 64;
      if (tp) __syncthreads();  // Lt reads of pass 0 done before SB reuse
      f4_t acc[2][2] = {};
      mloop<POST + 1, 2, 2>(role, POST, pq, pq, n0, NC2, (w & 1) * 32,
                            (w >> 1) * 32, S, WP, SB, acc);
      __syncthreads();
#pragma unroll
      for (int mi = 0; mi < 2; ++mi)
#pragma unroll
        for (int nj = 0; nj < 2; ++nj)
#pragma unroll
          for (int r = 0; r < 4; ++r)
            Lt[((w >> 1) * 32 + nj * 16 + lm) * 65 + (w & 1) * 32 + mi * 16 +
               lk * 4 + r] = acc[mi][nj][r];
      __syncthreads();
      int nl = tid >> 2, cq = (tid & 3) * 16;
      int n = n0 + nl;
      size_t off;
      const float* bias;
      int bq = cq;
      if (role == 1) { off = (size_t)R2G + (size_t)pq * 53248 + (size_t)n * 64 + cq; bias = b2; }
      else if (role == 2) { off = (size_t)R3G + (size_t)pq * 53248 + (size_t)n * 64 + cq; bias = b3; }
      else { off = (size_t)R4G + (size_t)n * 256 + pq * 64 + cq; bias = b4; bq = pq * 64 + cq; }
      const float* lp = Lt + nl * 65 + cq;
#pragma unroll
      for (int half = 0; half < 2; ++half) {
        size_t o8 = off + half * 8;
        bf8_t oh = *(const bf8_t*)&S[o8];
        bf8_t rh, rl;
#pragma unroll
        for (int e = 0; e < 8; ++e) {
          float v = lp[half * 8 + e];
          if (n == 784) v += bias[bq + half * 8 + e];
          float old = b2f((ushort_t)oh[e]);
          if (POST) {
            float nv = 0.5f * old - v;
            ushort_t h, l2; bsplit(nv, h, l2);
            rh[e] = (short)h; rl[e] = (short)l2;
          } else {
            rh[e] = (short)bround(0.5f * old + 0.5f * v);
          }
        }
        *(bf8_t*)&D[o8] = rh;
        if (POST) *(bf8_t*)&D[o8 + SELG] = rl;
      }
    }
  }
}

// H-GEMM: HpT[z][n][j] = sum_d P[d][j] S[d][n] (partials); 128x128 tiles,
// grid (7,7,9), MI=4/NJ=4 per wave, depth-2 register pipeline.
__device__ __forceinline__ void hstep(int s, size_t& base, int& C, int& c0) {
  if (s < 196) { base = R1G + (size_t)s * 26624; C = 32; c0 = 0; }
  else if (s < 294) { int u = s - 196; base = R2G + (size_t)(u >> 1) * 53248; C = 64; c0 = (u & 1) * 32; }
  else if (s < 392) { int u = s - 294; base = R3G + (size_t)(u >> 1) * 53248; C = 64; c0 = (u & 1) * 32; }
  else { base = R4G; C = 256; c0 = (s - 392) * 32; }
}

struct HF { bf8_t ah[4]; bf8_t al[4]; bf8_t b[4]; };

__device__ __forceinline__ void hload(HF& F, int s, int m0, int n0, int lm, int koff,
                                      const ushort_t* __restrict__ P,
                                      const ushort_t* __restrict__ S) {
  size_t base; int C, c0;
  hstep(s, base, C, c0);
#pragma unroll
  for (int mi = 0; mi < 4; ++mi) {
    const ushort_t* Am = P + base + (size_t)(m0 + mi * 16 + lm) * C + c0 + koff;
    F.ah[mi] = *(const bf8_t*)Am;
    F.al[mi] = *(const bf8_t*)(Am + SELG);
  }
#pragma unroll
  for (int nj = 0; nj < 4; ++nj)
    F.b[nj] = *(const bf8_t*)(S + base + (size_t)(n0 + nj * 16 + lm) * C + c0 + koff);
}

__device__ __forceinline__ void hmfma(HF& F, f4_t (&acc)[4][4]) {
#pragma unroll
  for (int mi = 0; mi < 4; ++mi)
#pragma unroll
    for (int nj = 0; nj < 4; ++nj) {
      acc[mi][nj] = MFMA16(F.ah[mi], F.b[nj], acc[mi][nj], 0, 0, 0);
      acc[mi][nj] = MFMA16(F.al[mi], F.b[nj], acc[mi][nj], 0, 0, 0);
    }
}

__global__ __launch_bounds__(256) void k_hgemm(float* __restrict__ HpT,
                                               const ushort_t* __restrict__ P,
                                               const ushort_t* __restrict__ S) {
  int tid = threadIdx.x, l = tid & 63, w = tid >> 6;
  int lm = l & 15, lk = l >> 4, koff = lk * 8;
  int m0 = blockIdx.y * 128 + (w & 1) * 64;
  int n0 = blockIdx.x * 128 + (w >> 1) * 64;
  int z = blockIdx.z;
  int s0 = (400 * z) / 9, s1e = (400 * (z + 1)) / 9;
  int ns = s1e - s0;
  f4_t acc[4][4] = {};
  HF F0, F1;
  hload(F0, s0, m0, n0, lm, koff, P, S);
  hload(F1, (ns > 1) ? s0 + 1 : s0, m0, n0, lm, koff, P, S);
  int t = 0;
  for (; t + 2 <= ns; t += 2) {
    hmfma(F0, acc);
    hload(F0, (s0 + t + 2 < s1e) ? s0 + t + 2 : s1e - 1, m0, n0, lm, koff, P, S);
    hmfma(F1, acc);
    hload(F1, (s0 + t + 3 < s1e) ? s0 + t + 3 : s1e - 1, m0, n0, lm, koff, P, S);
  }
  if (t < ns) hmfma(F0, acc);
#pragma unroll
  for (int mi = 0; mi < 4; ++mi)
#pragma unroll
    for (int nj = 0; nj < 4; ++nj)
#pragma unroll
      for (int r = 0; r < 4; ++r) {
        int m = m0 + mi * 16 + lk * 4 + r;
        int n = n0 + nj * 16 + lm;
        if (m < NBn && n < NBn)
          HpT[((size_t)z * NBn + n) * NBn + m] = acc[mi][nj][r];
      }
}

// sum partials -> Ht hi/lo bf16 (Ht[n][j] = H[j][n])
__global__ void k_combT(ushort_t* __restrict__ HtH, ushort_t* __restrict__ HtL,
                        const float* __restrict__ HpT) {
  int idx = blockIdx.x * blockDim.x + threadIdx.x;
  if (idx >= NBn * NBn) return;
  float s = 0.f;
#pragma unroll
  for (int z = 0; z < 9; ++z) s += HpT[(size_t)z * NBn * NBn + idx];
  ushort_t h, l; bsplit(s, h, l);
  HtH[idx] = h; HtL[idx] = l;
}

// x~ hi/lo planes [Bn][832]: col 784 = 1.0 (affine), pads 0
__global__ void k_xsplit(ushort_t* __restrict__ XH, ushort_t* __restrict__ XL,
                         const float* __restrict__ x, int Bn) {
  int idx = blockIdx.x * blockDim.x + threadIdx.x;
  if (idx >= Bn * NBn) return;
  int i = idx / NBn, j = idx % NBn;
  float v = (j < 784) ? x[(size_t)i * 784 + j] : (j == 784 ? 1.f : 0.f);
  ushort_t h, l; bsplit(v, h, l);
  XH[idx] = h; XL[idx] = l;
}

// Y[i][n] = sum_j x~[i][j] H[j][n]  (MFMA hi/lo: xh*Hh + xh*Hl + xl*Hh)
__global__ __launch_bounds__(256) void k_ygemm(float* __restrict__ Y,
    const ushort_t* __restrict__ XH, const ushort_t* __restrict__ XL,
    const ushort_t* __restrict__ HtH, const ushort_t* __restrict__ HtL, int Bn) {
  int tid = threadIdx.x, l = tid & 63, w = tid >> 6;
  int lm = l & 15, lk = l >> 4, koff = lk * 8;
  int m0 = blockIdx.y * 64 + (w & 1) * 32;
  int n0 = blockIdx.x * 64 + (w >> 1) * 32;
  f4_t acc[2][2] = {};
  for (int k0 = 0; k0 < NBn; k0 += 32) {
    bf8_t bh[2], bl[2];
#pragma unroll
    for (int nj = 0; nj < 2; ++nj) {
      size_t bo = (size_t)(n0 + nj * 16 + lm) * NBn + k0 + koff;
      bh[nj] = *(const bf8_t*)(HtH + bo);
      bl[nj] = *(const bf8_t*)(HtL + bo);
    }
#pragma unroll
    for (int mi = 0; mi < 2; ++mi) {
      int mrow = m0 + mi * 16 + lm;
      if (mrow >= Bn) mrow = Bn - 1;
      size_t ao = (size_t)mrow * NBn + k0 + koff;
      bf8_t ah = *(const bf8_t*)(XH + ao);
      bf8_t al = *(const bf8_t*)(XL + ao);
#pragma unroll
      for (int nj = 0; nj < 2; ++nj) {
        acc[mi][nj] = MFMA16(ah, bh[nj], acc[mi][nj], 0, 0, 0);
        acc[mi][nj] = MFMA16(ah, bl[nj], acc[mi][nj], 0, 0, 0);
        acc[mi][nj] = MFMA16(al, bh[nj], acc[mi][nj], 0, 0, 0);
      }
    }
  }
#pragma unroll
  for (int mi = 0; mi < 2; ++mi)
#pragma unroll
    for (int nj = 0; nj < 2; ++nj)
#pragma unroll
      for (int r = 0; r < 4; ++r) {
        int m = m0 + mi * 16 + lk * 4 + r;
        int n = n0 + nj * 16 + lm;
        if (m < Bn) Y[(size_t)m * NBn + n] = acc[mi][nj][r];
      }
}

// out[i] = 0.5||x_i||^2 - vb.x_i + sum_{j<784} x_ij Y[i,j] + Y[i,784]
__global__ void k_out(float* __restrict__ out, const float* __restrict__ x,
                      const float* __restrict__ vb, const float* __restrict__ Y, int Bn) {
  int wave = threadIdx.x >> 6, lane = threadIdx.x & 63;
  int i = blockIdx.x * 4 + wave;
  if (i >= Bn) return;
  const float* xi = x + (size_t)i * 784;
  const float* yi = Y + (size_t)i * NBn;
  float s = 0.f;
  for (int j = lane; j < 784; j += 64) {
    float xv = xi[j];
    s += xv * (0.5f * xv - vb[j] + yi[j]);
  }
  for (int off = 32; off; off >>= 1) s += __shfl_down(s, off);
  if (lane == 0) out[i] = s + yi[784];
}

extern "C" void kernel_launch(void* const* d_in, const int* in_sizes, int n_in, void* d_out,
                              int out_size, void* d_ws, size_t ws_size, hipStream_t stream) {
  const float* x  = (const float*)d_in[0];
  const float* vb = (const float*)d_in[1];
  const float* w1 = (const float*)d_in[2];
  const float* b1 = (const float*)d_in[3];
  const float* w2 = (const float*)d_in[4];
  const float* b2 = (const float*)d_in[5];
  const float* w3 = (const float*)d_in[6];
  const float* b3 = (const float*)d_in[7];
  const float* w4 = (const float*)d_in[8];
  const float* b4 = (const float*)d_in[9];
  int Bn = in_sizes[0] / 784;
  float* out = (float*)d_out;

  ushort_t* S0 = (ushort_t*)d_ws;                    // SELG (single plane)
  ushort_t* S1 = S0 + (size_t)SELG;                  // SELG; reused as HpT later
  ushort_t* Pb = S1 + (size_t)SELG;                  // 2*SELG (hi/lo); reused as XH/XL
  ushort_t* G  = Pb + (size_t)2 * SELG;              // 2*GPL; reused as Y later
  ushort_t* WP = G + (size_t)2 * GPL;                // WPTOT2
  ushort_t* HtH = WP + WPTOT2;                       // NBn*NBn
  ushort_t* HtL = HtH + (size_t)NBn * NBn;           // NBn*NBn
  float* HpT = (float*)S1;                           // 9*NBn*NBn f32
  ushort_t* XH = Pb;                                 // Bn*NBn (Pb dead after hgemm)
  ushort_t* XL = XH + (size_t)Bn * NBn;
  float* Y = (float*)G;                              // Bn*NBn f32

  const int TB = 256;
  k_fill0<<<2048, TB, 0, stream>>>((float*)S0, SELG / 2);
  k_fill0<<<2048, TB, 0, stream>>>((float*)S1, SELG / 2);
  k_fill0<<<2, TB, 0, stream>>>((float*)(WP + ZOFF), 1280);
  k_pack2<<<72, TB, 0, stream>>>(w2, WP);
  k_pack3<<<144, TB, 0, stream>>>(w3, WP);
  k_pack4<<<3136, TB, 0, stream>>>(w4, WP);
  k_u1b<<<20384, TB, 0, stream>>>(G, w1, b1);

  ushort_t* cur = S0;
  ushort_t* nxt = S1;
  for (int it = 0; it < NITER; ++it) {
    k_mega<0><<<1351, TB, 0, stream>>>(cur, nxt, G, WP, b2, b3, b4);
    ushort_t* t = cur; cur = nxt; nxt = t;
  }
  // cur == S0 (50 swaps even)

  // post fields P into Pb (hi/lo)
  k_p1<<<2548, TB, 0, stream>>>(Pb, cur, G);
  k_mega<1><<<714, TB, 0, stream>>>(cur, Pb, G, WP, b2, b3, b4);

  // H partials (transposed, split-K 9) -> Ht hi/lo
  k_hgemm<<<dim3(7, 7, 9), TB, 0, stream>>>(HpT, Pb, cur);
  k_combT<<<(NBn * NBn + TB - 1) / TB, TB, 0, stream>>>(HtH, HtL, HpT);

  // Y = x~ * H via MFMA, then out
  k_xsplit<<<(Bn * NBn + TB - 1) / TB, TB, 0, stream>>>(XH, XL, x, Bn);
  k_ygemm<<<dim3(13, (Bn + 63) / 64), TB, 0, stream>>>(Y, XH, XL, HtH, HtL, Bn);
  k_out<<<(Bn + 3) / 4, TB, 0, stream>>>(out, x, vb, Y, Bn);
}

// Round 16
// 3529.251 us; speedup vs baseline: 1.3228x; 1.3228x over previous
//
#include <hip/hip_runtime.h>
#include <cstddef>

// Basis-propagation; iteration in PURE bf16, post-fields/H/Y in bf16 hi/lo.
// State S[pos][n][c] channel-minor, guard bands; invalid taps = zero-weight.
// R16 = R14 exact revert (best: 3533us). R15's serialization experiment
// proved k_mega is per-block latency-bound (traffic halved, time doubled);
// R14's config is the optimum of the explored space.
// Role-0 2x2 patch; roles 1-3 depth-4 pipeline; nt-major + XCD swizzle;
// k_hgemm 128x128 grid (7,7,9).

typedef unsigned short ushort_t;
typedef __attribute__((ext_vector_type(8))) short bf8_t;   // 8 bf16
typedef __attribute__((ext_vector_type(4))) float f4_t;

#define MFMA16 __builtin_amdgcn_mfma_f32_16x16x32_bf16

#define NBn 832
#define NITER 50
#define GPL 5218304u       // u1/G plane size (196*26624)

// state plane geometry (elems), with guards:
#define SELG 13125632u
#define R1G 399360
#define R2G 6043648
#define R3G 9877504
#define R4G 12912640

// packed weights (elems; each matrix = [hi plane][lo plane])
#define W2F_OFF 0u
#define W2B_OFF 36864u
#define W3F_OFF 73728u
#define W3B_OFF 147456u
#define W4P_OFF 221184u
#define W4Q_OFF 1826816u
#define W2PL 18432u
#define W3PL 36864u
#define W4PL 802816u
#define ZOFF 3432448u
#define WPTOT2 3435008u

__device__ __forceinline__ void bsplit(float v, ushort_t& h, ushort_t& lo) {
  union { float f; unsigned u; } a; a.f = v;
  unsigned uh = (a.u + 0x7fffu + ((a.u >> 16) & 1u)) & 0xffff0000u;
  h = (ushort_t)(uh >> 16);
  union { unsigned u; float f; } b; b.u = uh;
  float r = v - b.f;
  union { float f; unsigned u; } c; c.f = r;
  lo = (ushort_t)((c.u + 0x7fffu + ((c.u >> 16) & 1u)) >> 16);
}

__device__ __forceinline__ ushort_t bround(float v) {
  union { float f; unsigned u; } a; a.f = v;
  return (ushort_t)((a.u + 0x7fffu + ((a.u >> 16) & 1u)) >> 16);
}

__device__ __forceinline__ float b2f(ushort_t h) {
  union { unsigned u; float f; } a; a.u = ((unsigned)h) << 16;
  return a.f;
}

__device__ __forceinline__ float bjoin(ushort_t h, ushort_t l) {
  return b2f(h) + b2f(l);
}

// bijective chunked XCD swizzle
__device__ __forceinline__ int xswz(int lin, int nwg) {
  int xcd = lin & 7, o = lin >> 3;
  int q = nwg >> 3, r = nwg & 7;
  return (xcd < r) ? (xcd * (q + 1) + o) : (r * (q + 1) + (xcd - r) * q + o);
}

__global__ void k_fill0(float* p, unsigned n) {
  for (unsigned i = blockIdx.x * blockDim.x + threadIdx.x; i < n;
       i += gridDim.x * blockDim.x)
    p[i] = 0.f;
}

__global__ void k_pack2(const float* __restrict__ w2, ushort_t* __restrict__ WP) {
  int idx = blockIdx.x * blockDim.x + threadIdx.x;
  if (idx >= 18432) return;
  int co = idx / 288, rem = idx % 288, ci = rem / 9, t = rem % 9;
  ushort_t h, l; bsplit(w2[idx], h, l);
  unsigned f = W2F_OFF + t * 2048 + co * 32 + ci;
  unsigned b = W2B_OFF + t * 2048 + ci * 64 + co;
  WP[f] = h; WP[f + W2PL] = l;
  WP[b] = h; WP[b + W2PL] = l;
}

__global__ void k_pack3(const float* __restrict__ w3, ushort_t* __restrict__ WP) {
  int idx = blockIdx.x * blockDim.x + threadIdx.x;
  if (idx >= 36864) return;
  int co = idx / 576, rem = idx % 576, ci = rem / 9, t = rem % 9;
  ushort_t h, l; bsplit(w3[idx], h, l);
  unsigned f = W3F_OFF + t * 4096 + co * 64 + ci;
  unsigned b = W3B_OFF + t * 4096 + ci * 64 + co;
  WP[f] = h; WP[f + W3PL] = l;
  WP[b] = h; WP[b + W3PL] = l;
}

__global__ void k_pack4(const float* __restrict__ w4, ushort_t* __restrict__ WP) {
  int idx = blockIdx.x * blockDim.x + threadIdx.x;
  if (idx >= 802816) return;
  int o = idx / 3136, kk = idx % 3136, c = kk / 49, p = kk % 49;
  ushort_t h, l; bsplit(w4[idx], h, l);
  unsigned a = W4P_OFF + p * 16384 + c * 256 + o;
  unsigned b = W4Q_OFF + o * 3136 + p * 64 + c;
  WP[a] = h; WP[a + W4PL] = l;
  WP[b] = h; WP[b + W4PL] = l;
}

// u1[q][n][c]: conv1 of basis vector n (n==784 -> b1, pads 0), split bf16
__global__ void k_u1b(ushort_t* __restrict__ G, const float* __restrict__ w1,
                      const float* __restrict__ b1) {
  unsigned idx = blockIdx.x * blockDim.x + threadIdx.x;
  if (idx >= GPL) return;
  int q = idx / 26624, rem = idx % 26624, n = rem / 32, c = rem % 32;
  int oy = q / 14, ox = q % 14;
  float v = 0.f;
  if (n < 784) {
    int py = n / 28, px = n % 28;
    int ky = py - (2 * oy - 1), kx = px - (2 * ox - 1);
    if (ky >= 0 && ky < 3 && kx >= 0 && kx < 3) v = w1[c * 9 + ky * 3 + kx];
  } else if (n == 784) {
    v = b1[c];
  }
  ushort_t h, l; bsplit(v, h, l);
  G[idx] = h; G[idx + GPL] = l;
}

// P1 = 0.5*s1_final - u1  (hi/lo into Pb)
__global__ void k_p1(ushort_t* __restrict__ D, const ushort_t* __restrict__ S,
                     const ushort_t* __restrict__ G) {
  unsigned g8 = (blockIdx.x * blockDim.x + threadIdx.x) * 8;
  if (g8 >= GPL) return;
  size_t off = (size_t)R1G + g8;
  bf8_t oh = *(const bf8_t*)&S[off];
  bf8_t gh = *(const bf8_t*)&G[g8], gl = *(const bf8_t*)&G[g8 + GPL];
  bf8_t rh, rl;
#pragma unroll
  for (int e = 0; e < 8; ++e) {
    float v = 0.5f * b2f((ushort_t)oh[e]) -
              bjoin((ushort_t)gh[e], (ushort_t)gl[e]);
    ushort_t h, l; bsplit(v, h, l);
    rh[e] = (short)h; rl[e] = (short)l;
  }
  *(bf8_t*)&D[off] = rh;
  *(bf8_t*)&D[off + SELG] = rl;
}

// ---- chunk descriptors (roles 1-3) ----
struct Ent { unsigned eh, el; int b; int ars, brs; };

__device__ __forceinline__ Ent entry(int role, int e, int p, int mt, int post) {
  Ent E;
  if (role == 3) {
    E.eh = W4Q_OFF + ((unsigned)mt * 64u) * 3136u + (unsigned)e * 32u;
    E.el = E.eh + W4PL;
    E.b = R3G + (e >> 1) * 53248 + (e & 1) * 32;
    E.ars = 3136; E.brs = 64;
  } else if (role == 2) {
    int y = p / 7, x = p % 7;
    if (e < 18) {
      int t = e >> 1, sub = e & 1, ky = t / 3, kx = t % 3;
      int iy = y - 1 + ky, ix = x - 1 + kx;
      bool v = (iy >= 0 && iy < 7 && ix >= 0 && ix < 7);
      E.eh = v ? (W3F_OFF + t * 4096u + sub * 32u) : ZOFF;
      E.el = v ? (E.eh + W3PL) : ZOFF;
      E.b = R2G + (iy * 7 + ix) * 53248 + sub * 32;
      E.ars = v ? 64 : 32; E.brs = 64;
    } else {
      int s = e - 18;
      E.eh = W4P_OFF + (unsigned)p * 16384u + s * 32u;
      E.el = E.eh + W4PL;
      E.b = R4G + s * 32;
      E.ars = 256; E.brs = 256;
    }
  } else {  // role 1
    int y = p / 7, x = p % 7;
    if (e < 9) {
      int ky = e / 3, kx = e % 3;
      int iy = 2 * y - 1 + ky, ix = 2 * x - 1 + kx;
      bool v = (iy >= 0 && iy < 14 && ix >= 0 && ix < 14);
      E.eh = v ? (W2F_OFF + e * 2048u) : ZOFF;
      E.el = v ? (E.eh + W2PL) : ZOFF;
      E.b = R1G + (iy * 14 + ix) * 26624;
      E.ars = 32; E.brs = 32;
    } else if (e < 27 && !post) {
      int u = e - 9, t = u >> 1, sub = u & 1, ky = t / 3, kx = t % 3;
      int ty = y + 1 - ky, tx = x + 1 - kx;
      bool v = (ty >= 0 && ty < 7 && tx >= 0 && tx < 7);
      E.eh = v ? (W3B_OFF + t * 4096u + sub * 32u) : ZOFF;
      E.el = v ? (E.eh + W3PL) : ZOFF;
      E.b = R3G + (ty * 7 + tx) * 53248 + sub * 32;
      E.ars = v ? 64 : 32; E.brs = 64;
    } else {
      E.eh = ZOFF; E.el = ZOFF; E.b = R4G; E.ars = 32; E.brs = 256;
    }
  }
  return E;
}

__device__ __forceinline__ Ent entryg(int role, int e, int p, int mt, int post,
                                      int elim) {
  if (e >= elim) {
    Ent E; E.eh = ZOFF; E.el = ZOFF; E.b = R4G; E.ars = 32; E.brs = 256;
    return E;
  }
  return entry(role, e, p, mt, post);
}

template <int APL, int MI>
__device__ __forceinline__ void loadA(bf8_t (&A0)[MI][APL], bf8_t (&A1)[MI][APL],
                                      int role, int e0, int p, int mt, int post,
                                      int elim, int mhalf, int lm, int koff,
                                      const ushort_t* __restrict__ WP) {
  Ent E0 = entryg(role, e0, p, mt, post, elim);
  Ent E1 = entryg(role, e0 + 1, p, mt, post, elim);
#pragma unroll
  for (int mi = 0; mi < MI; ++mi) {
    int mo0 = (mhalf + mi * 16 + lm) * E0.ars + koff;
    int mo1 = (mhalf + mi * 16 + lm) * E1.ars + koff;
    A0[mi][0] = *(const bf8_t*)(WP + E0.eh + mo0);
    A1[mi][0] = *(const bf8_t*)(WP + E1.eh + mo1);
    if (APL == 2) {
      A0[mi][APL - 1] = *(const bf8_t*)(WP + E0.el + mo0);
      A1[mi][APL - 1] = *(const bf8_t*)(WP + E1.el + mo1);
    }
  }
}

__device__ __forceinline__ void loadB(bf8_t& s0, bf8_t& s1, int role, int e0,
                                      int p, int mt, int post, int elim, int n0,
                                      int sn, int sc,
                                      const ushort_t* __restrict__ S) {
  Ent E0 = entryg(role, e0, p, mt, post, elim);
  Ent E1 = entryg(role, e0 + 1, p, mt, post, elim);
  s0 = *(const bf8_t*)(S + E0.b + (n0 + sn) * E0.brs + sc);
  s1 = *(const bf8_t*)(S + E1.b + (n0 + sn) * E1.brs + sc);
}

template <int APL, int MI, int NJ>
__device__ __forceinline__ void mfmaset(const bf8_t (&A0)[MI][APL],
                                        const bf8_t (&A1)[MI][APL],
                                        const ushort_t* __restrict__ Bb, int nhalf,
                                        int lm, int koff, f4_t (&acc)[MI][NJ]) {
#pragma unroll
  for (int nj = 0; nj < NJ; ++nj) {
    int lo = (nhalf + nj * 16 + lm) * 40 + koff;
    bf8_t b0 = *(const bf8_t*)&Bb[lo];
    bf8_t b1 = *(const bf8_t*)&Bb[2560 + lo];
#pragma unroll
    for (int mi = 0; mi < MI; ++mi)
#pragma unroll
      for (int pl = 0; pl < APL; ++pl) {
        acc[mi][nj] = MFMA16(A0[mi][pl], b0, acc[mi][nj], 0, 0, 0);
        acc[mi][nj] = MFMA16(A1[mi][pl], b1, acc[mi][nj], 0, 0, 0);
      }
  }
}

// depth-4 B staging pipeline (roles 1-3)
template <int APL, int MI, int NJ>
__device__ __forceinline__ void mloop(int role, int post, int p, int mt, int n0,
                                      int NC2, int mhalf, int nhalf,
                                      const ushort_t* __restrict__ S,
                                      const ushort_t* __restrict__ WP,
                                      ushort_t* __restrict__ SB,
                                      f4_t (&acc)[MI][NJ]) {
  const int tid = threadIdx.x, l = tid & 63;
  const int lm = l & 15, koff = (l >> 4) * 8;
  const int sn = tid >> 2, sc = (tid & 3) * 8;
  const int elim = 2 * NC2;
  bf8_t bs0[4], bs1[4];
#pragma unroll
  for (int q = 0; q < 4; ++q)
    loadB(bs0[q], bs1[q], role, 2 * q, p, mt, post, elim, n0, sn, sc, S);
  bf8_t aE0[MI][APL], aE1[MI][APL], aO0[MI][APL], aO1[MI][APL];
  loadA<APL, MI>(aE0, aE1, role, 0, p, mt, post, elim, mhalf, lm, koff, WP);
  loadA<APL, MI>(aO0, aO1, role, 2, p, mt, post, elim, mhalf, lm, koff, WP);
  {
    int wb = sn * 40 + sc;
    *(bf8_t*)&SB[wb] = bs0[0];
    *(bf8_t*)&SB[wb + 2560] = bs1[0];
  }
  __syncthreads();
  const int ntrip = (NC2 + 3) >> 2;
  for (int t4 = 0; t4 < ntrip; ++t4) {
    int j4 = t4 * 4;
#pragma unroll
    for (int pp = 0; pp < 4; ++pp) {
      int jj = j4 + pp;
      loadB(bs0[pp], bs1[pp], role, 2 * (jj + 4), p, mt, post, elim, n0, sn, sc, S);
      const ushort_t* Bb = SB + (pp & 1) * 5120;
      if ((pp & 1) == 0) {
        mfmaset<APL, MI, NJ>(aE0, aE1, Bb, nhalf, lm, koff, acc);
        loadA<APL, MI>(aE0, aE1, role, 2 * (jj + 2), p, mt, post, elim, mhalf, lm,
                       koff, WP);
      } else {
        mfmaset<APL, MI, NJ>(aO0, aO1, Bb, nhalf, lm, koff, acc);
        loadA<APL, MI>(aO0, aO1, role, 2 * (jj + 2), p, mt, post, elim, mhalf, lm,
                       koff, WP);
      }
      {
        int wb = sn * 40 + sc;
        ushort_t* Wb = SB + ((pp + 1) & 1) * 5120;
        *(bf8_t*)&Wb[wb] = bs0[(pp + 1) & 3];
        *(bf8_t*)&Wb[wb + 2560] = bs1[(pp + 1) & 3];
      }
      __syncthreads();
    }
  }
}

// mega kernel: iter blocks [role3 52][role2 637][role1 637][role0-patch 637]
// post blocks [role3 52][role2 637][role1 637]
template <int POST>
__global__ __launch_bounds__(256) void k_mega(
    const ushort_t* __restrict__ S, ushort_t* __restrict__ D,
    const ushort_t* __restrict__ G, const ushort_t* __restrict__ WP,
    const float* __restrict__ b2, const float* __restrict__ b3,
    const float* __restrict__ b4) {
  __shared__ __align__(16) ushort_t SB[20480];  // role0: 8 B-ents; 1-3: dbuf
  float* Lt = (float*)SB;
  const int tid = threadIdx.x, l = tid & 63, w = tid >> 6;
  const int lm = l & 15, lk = l >> 4;
  int b = blockIdx.x;
  int role, rb, ntile, pq;
  if (b < 52) { role = 3; rb = xswz(b, 52); ntile = rb >> 2; pq = rb & 3; }
  else if (b < 689) { role = 2; rb = xswz(b - 52, 637); ntile = rb / 49; pq = rb % 49; }
  else if (b < 1326) { role = 1; rb = xswz(b - 689, 637); ntile = rb / 49; pq = rb % 49; }
  else { role = 0; rb = xswz(b - 1326, 637); ntile = rb / 49; pq = rb % 49; }

  int n0 = ntile * 64;

  if (role == 0) {
    // 2x2 patch at (Y,X) on the 7x7 patch grid; positions (2Y+py, 2X+px).
    const int Y = pq / 7, X = pq % 7;
    const int sn = tid >> 2, sc = (tid & 3) * 8;
    const int koff = lk * 8;
    bf8_t breg[8];
#pragma unroll
    for (int e = 0; e < 8; ++e) {
      int t2 = e >> 1, dy = t2 >> 1, dx = t2 & 1, sub = e & 1;
      bool tv = (Y + dy < 7) && (X + dx < 7);
      int bbase = tv ? (R2G + ((Y + dy) * 7 + (X + dx)) * 53248 + sub * 32) : R4G;
      breg[e] = *(const bf8_t*)(S + bbase + (n0 + sn) * 64 + sc);
    }
    {
      int wb = sn * 40 + sc;
#pragma unroll
      for (int e = 0; e < 8; ++e) *(bf8_t*)&SB[e * 2560 + wb] = breg[e];
    }
    __syncthreads();
    f4_t acc[4][2] = {};
    const int nloc = w * 16 + lm;
#pragma unroll
    for (int e = 0; e < 8; ++e) {
      int t2 = e >> 1, dy = t2 >> 1, dx = t2 & 1, sub = e & 1;
      bool tv = (Y + dy < 7) && (X + dx < 7);
      bf8_t bfr = *(const bf8_t*)&SB[e * 2560 + nloc * 40 + koff];
#pragma unroll
      for (int py = 0; py < 2; ++py) {
#pragma unroll
        for (int px = 0; px < 2; ++px) {
          const int ky = py + 1 - 2 * dy, kx = px + 1 - 2 * dx;
          if (ky >= 0 && kx >= 0) {  // compile-time after unroll
            unsigned abase = tv ? (W2B_OFF + (unsigned)(ky * 3 + kx) * 2048u +
                                   (unsigned)sub * 32u)
                                : ZOFF;
            const int pos = py * 2 + px;
#pragma unroll
            for (int mi = 0; mi < 2; ++mi) {
              bf8_t afr = *(const bf8_t*)(WP + abase + (mi * 16 + lm) * 64 + koff);
              acc[pos][mi] = MFMA16(afr, bfr, acc[pos][mi], 0, 0, 0);
            }
          }
        }
      }
    }
#pragma unroll
    for (int pos = 0; pos < 4; ++pos) {
      __syncthreads();
#pragma unroll
      for (int mi = 0; mi < 2; ++mi)
#pragma unroll
        for (int r = 0; r < 4; ++r)
          Lt[(w * 16 + lm) * 33 + mi * 16 + lk * 4 + r] = acc[pos][mi][r];
      __syncthreads();
      int q = (2 * Y + (pos >> 1)) * 14 + 2 * X + (pos & 1);
      int nl = tid >> 2, cq = (tid & 3) * 8;
      int n = n0 + nl;
      size_t off = (size_t)R1G + (size_t)q * 26624 + (size_t)n * 32 + cq;
      size_t goff = (size_t)q * 26624 + (size_t)n * 32 + cq;
      bf8_t oh = *(const bf8_t*)&S[off];
      bf8_t gh = *(const bf8_t*)&G[goff], gl = *(const bf8_t*)&G[goff + GPL];
      const float* lp = Lt + nl * 33 + cq;
      bf8_t rh;
#pragma unroll
      for (int e = 0; e < 8; ++e) {
        float old = b2f((ushort_t)oh[e]);
        float u = bjoin((ushort_t)gh[e], (ushort_t)gl[e]);
        rh[e] = (short)bround(0.5f * old + 0.5f * (lp[e] + u));
      }
      *(bf8_t*)&D[off] = rh;
    }
  } else {
    f4_t acc[2][2] = {};
    int NC2 = (role == 3) ? 49 : (role == 2) ? (POST ? 9 : 13) : (POST ? 5 : 14);
    mloop<POST + 1, 2, 2>(role, POST, pq, pq, n0, NC2, (w & 1) * 32, (w >> 1) * 32,
                          S, WP, SB, acc);
    __syncthreads();
#pragma unroll
    for (int mi = 0; mi < 2; ++mi)
#pragma unroll
      for (int nj = 0; nj < 2; ++nj)
#pragma unroll
        for (int r = 0; r < 4; ++r)
          Lt[((w >> 1) * 32 + nj * 16 + lm) * 65 + (w & 1) * 32 + mi * 16 + lk * 4 + r] =
              acc[mi][nj][r];
    __syncthreads();
    int nl = tid >> 2, cq = (tid & 3) * 16;
    int n = n0 + nl;
    size_t off;
    const float* bias;
    int bq = cq;
    if (role == 1) { off = (size_t)R2G + (size_t)pq * 53248 + (size_t)n * 64 + cq; bias = b2; }
    else if (role == 2) { off = (size_t)R3G + (size_t)pq * 53248 + (size_t)n * 64 + cq; bias = b3; }
    else { off = (size_t)R4G + (size_t)n * 256 + pq * 64 + cq; bias = b4; bq = pq * 64 + cq; }
    const float* lp = Lt + nl * 65 + cq;
#pragma unroll
    for (int half = 0; half < 2; ++half) {
      size_t o8 = off + half * 8;
      bf8_t oh = *(const bf8_t*)&S[o8];
      bf8_t rh, rl;
#pragma unroll
      for (int e = 0; e < 8; ++e) {
        float v = lp[half * 8 + e];
        if (n == 784) v += bias[bq + half * 8 + e];
        float old = b2f((ushort_t)oh[e]);
        if (POST) {
          float nv = 0.5f * old - v;
          ushort_t h, l2; bsplit(nv, h, l2);
          rh[e] = (short)h; rl[e] = (short)l2;
        } else {
          rh[e] = (short)bround(0.5f * old + 0.5f * v);
        }
      }
      *(bf8_t*)&D[o8] = rh;
      if (POST) *(bf8_t*)&D[o8 + SELG] = rl;
    }
  }
}

// H-GEMM: HpT[z][n][j] = sum_d P[d][j] S[d][n] (partials); 128x128 tiles,
// grid (7,7,9), MI=4/NJ=4 per wave, depth-2 register pipeline.
__device__ __forceinline__ void hstep(int s, size_t& base, int& C, int& c0) {
  if (s < 196) { base = R1G + (size_t)s * 26624; C = 32; c0 = 0; }
  else if (s < 294) { int u = s - 196; base = R2G + (size_t)(u >> 1) * 53248; C = 64; c0 = (u & 1) * 32; }
  else if (s < 392) { int u = s - 294; base = R3G + (size_t)(u >> 1) * 53248; C = 64; c0 = (u & 1) * 32; }
  else { base = R4G; C = 256; c0 = (s - 392) * 32; }
}

struct HF { bf8_t ah[4]; bf8_t al[4]; bf8_t b[4]; };

__device__ __forceinline__ void hload(HF& F, int s, int m0, int n0, int lm, int koff,
                                      const ushort_t* __restrict__ P,
                                      const ushort_t* __restrict__ S) {
  size_t base; int C, c0;
  hstep(s, base, C, c0);
#pragma unroll
  for (int mi = 0; mi < 4; ++mi) {
    const ushort_t* Am = P + base + (size_t)(m0 + mi * 16 + lm) * C + c0 + koff;
    F.ah[mi] = *(const bf8_t*)Am;
    F.al[mi] = *(const bf8_t*)(Am + SELG);
  }
#pragma unroll
  for (int nj = 0; nj < 4; ++nj)
    F.b[nj] = *(const bf8_t*)(S + base + (size_t)(n0 + nj * 16 + lm) * C + c0 + koff);
}

__device__ __forceinline__ void hmfma(HF& F, f4_t (&acc)[4][4]) {
#pragma unroll
  for (int mi = 0; mi < 4; ++mi)
#pragma unroll
    for (int nj = 0; nj < 4; ++nj) {
      acc[mi][nj] = MFMA16(F.ah[mi], F.b[nj], acc[mi][nj], 0, 0, 0);
      acc[mi][nj] = MFMA16(F.al[mi], F.b[nj], acc[mi][nj], 0, 0, 0);
    }
}

__global__ __launch_bounds__(256) void k_hgemm(float* __restrict__ HpT,
                                               const ushort_t* __restrict__ P,
                                               const ushort_t* __restrict__ S) {
  int tid = threadIdx.x, l = tid & 63, w = tid >> 6;
  int lm = l & 15, lk = l >> 4, koff = lk * 8;
  int m0 = blockIdx.y * 128 + (w & 1) * 64;
  int n0 = blockIdx.x * 128 + (w >> 1) * 64;
  int z = blockIdx.z;
  int s0 = (400 * z) / 9, s1e = (400 * (z + 1)) / 9;
  int ns = s1e - s0;
  f4_t acc[4][4] = {};
  HF F0, F1;
  hload(F0, s0, m0, n0, lm, koff, P, S);
  hload(F1, (ns > 1) ? s0 + 1 : s0, m0, n0, lm, koff, P, S);
  int t = 0;
  for (; t + 2 <= ns; t += 2) {
    hmfma(F0, acc);
    hload(F0, (s0 + t + 2 < s1e) ? s0 + t + 2 : s1e - 1, m0, n0, lm, koff, P, S);
    hmfma(F1, acc);
    hload(F1, (s0 + t + 3 < s1e) ? s0 + t + 3 : s1e - 1, m0, n0, lm, koff, P, S);
  }
  if (t < ns) hmfma(F0, acc);
#pragma unroll
  for (int mi = 0; mi < 4; ++mi)
#pragma unroll
    for (int nj = 0; nj < 4; ++nj)
#pragma unroll
      for (int r = 0; r < 4; ++r) {
        int m = m0 + mi * 16 + lk * 4 + r;
        int n = n0 + nj * 16 + lm;
        if (m < NBn && n < NBn)
          HpT[((size_t)z * NBn + n) * NBn + m] = acc[mi][nj][r];
      }
}

// sum partials -> Ht hi/lo bf16 (Ht[n][j] = H[j][n])
__global__ void k_combT(ushort_t* __restrict__ HtH, ushort_t* __restrict__ HtL,
                        const float* __restrict__ HpT) {
  int idx = blockIdx.x * blockDim.x + threadIdx.x;
  if (idx >= NBn * NBn) return;
  float s = 0.f;
#pragma unroll
  for (int z = 0; z < 9; ++z) s += HpT[(size_t)z * NBn * NBn + idx];
  ushort_t h, l; bsplit(s, h, l);
  HtH[idx] = h; HtL[idx] = l;
}

// x~ hi/lo planes [Bn][832]: col 784 = 1.0 (affine), pads 0
__global__ void k_xsplit(ushort_t* __restrict__ XH, ushort_t* __restrict__ XL,
                         const float* __restrict__ x, int Bn) {
  int idx = blockIdx.x * blockDim.x + threadIdx.x;
  if (idx >= Bn * NBn) return;
  int i = idx / NBn, j = idx % NBn;
  float v = (j < 784) ? x[(size_t)i * 784 + j] : (j == 784 ? 1.f : 0.f);
  ushort_t h, l; bsplit(v, h, l);
  XH[idx] = h; XL[idx] = l;
}

// Y[i][n] = sum_j x~[i][j] H[j][n]  (MFMA hi/lo: xh*Hh + xh*Hl + xl*Hh)
__global__ __launch_bounds__(256) void k_ygemm(float* __restrict__ Y,
    const ushort_t* __restrict__ XH, const ushort_t* __restrict__ XL,
    const ushort_t* __restrict__ HtH, const ushort_t* __restrict__ HtL, int Bn) {
  int tid = threadIdx.x, l = tid & 63, w = tid >> 6;
  int lm = l & 15, lk = l >> 4, koff = lk * 8;
  int m0 = blockIdx.y * 64 + (w & 1) * 32;
  int n0 = blockIdx.x * 64 + (w >> 1) * 32;
  f4_t acc[2][2] = {};
  for (int k0 = 0; k0 < NBn; k0 += 32) {
    bf8_t bh[2], bl[2];
#pragma unroll
    for (int nj = 0; nj < 2; ++nj) {
      size_t bo = (size_t)(n0 + nj * 16 + lm) * NBn + k0 + koff;
      bh[nj] = *(const bf8_t*)(HtH + bo);
      bl[nj] = *(const bf8_t*)(HtL + bo);
    }
#pragma unroll
    for (int mi = 0; mi < 2; ++mi) {
      int mrow = m0 + mi * 16 + lm;
      if (mrow >= Bn) mrow = Bn - 1;
      size_t ao = (size_t)mrow * NBn + k0 + koff;
      bf8_t ah = *(const bf8_t*)(XH + ao);
      bf8_t al = *(const bf8_t*)(XL + ao);
#pragma unroll
      for (int nj = 0; nj < 2; ++nj) {
        acc[mi][nj] = MFMA16(ah, bh[nj], acc[mi][nj], 0, 0, 0);
        acc[mi][nj] = MFMA16(ah, bl[nj], acc[mi][nj], 0, 0, 0);
        acc[mi][nj] = MFMA16(al, bh[nj], acc[mi][nj], 0, 0, 0);
      }
    }
  }
#pragma unroll
  for (int mi = 0; mi < 2; ++mi)
#pragma unroll
    for (int nj = 0; nj < 2; ++nj)
#pragma unroll
      for (int r = 0; r < 4; ++r) {
        int m = m0 + mi * 16 + lk * 4 + r;
        int n = n0 + nj * 16 + lm;
        if (m < Bn) Y[(size_t)m * NBn + n] = acc[mi][nj][r];
      }
}

// out[i] = 0.5||x_i||^2 - vb.x_i + sum_{j<784} x_ij Y[i,j] + Y[i,784]
__global__ void k_out(float* __restrict__ out, const float* __restrict__ x,
                      const float* __restrict__ vb, const float* __restrict__ Y, int Bn) {
  int wave = threadIdx.x >> 6, lane = threadIdx.x & 63;
  int i = blockIdx.x * 4 + wave;
  if (i >= Bn) return;
  const float* xi = x + (size_t)i * 784;
  const float* yi = Y + (size_t)i * NBn;
  float s = 0.f;
  for (int j = lane; j < 784; j += 64) {
    float xv = xi[j];
    s += xv * (0.5f * xv - vb[j] + yi[j]);
  }
  for (int off = 32; off; off >>= 1) s += __shfl_down(s, off);
  if (lane == 0) out[i] = s + yi[784];
}

extern "C" void kernel_launch(void* const* d_in, const int* in_sizes, int n_in, void* d_out,
                              int out_size, void* d_ws, size_t ws_size, hipStream_t stream) {
  const float* x  = (const float*)d_in[0];
  const float* vb = (const float*)d_in[1];
  const float* w1 = (const float*)d_in[2];
  const float* b1 = (const float*)d_in[3];
  const float* w2 = (const float*)d_in[4];
  const float* b2 = (const float*)d_in[5];
  const float* w3 = (const float*)d_in[6];
  const float* b3 = (const float*)d_in[7];
  const float* w4 = (const float*)d_in[8];
  const float* b4 = (const float*)d_in[9];
  int Bn = in_sizes[0] / 784;
  float* out = (float*)d_out;

  ushort_t* S0 = (ushort_t*)d_ws;                    // SELG (single plane)
  ushort_t* S1 = S0 + (size_t)SELG;                  // SELG; reused as HpT later
  ushort_t* Pb = S1 + (size_t)SELG;                  // 2*SELG (hi/lo); reused as XH/XL
  ushort_t* G  = Pb + (size_t)2 * SELG;              // 2*GPL; reused as Y later
  ushort_t* WP = G + (size_t)2 * GPL;                // WPTOT2
  ushort_t* HtH = WP + WPTOT2;                       // NBn*NBn
  ushort_t* HtL = HtH + (size_t)NBn * NBn;           // NBn*NBn
  float* HpT = (float*)S1;                           // 9*NBn*NBn f32
  ushort_t* XH = Pb;                                 // Bn*NBn (Pb dead after hgemm)
  ushort_t* XL = XH + (size_t)Bn * NBn;
  float* Y = (float*)G;                              // Bn*NBn f32

  const int TB = 256;
  k_fill0<<<2048, TB, 0, stream>>>((float*)S0, SELG / 2);
  k_fill0<<<2048, TB, 0, stream>>>((float*)S1, SELG / 2);
  k_fill0<<<2, TB, 0, stream>>>((float*)(WP + ZOFF), 1280);
  k_pack2<<<72, TB, 0, stream>>>(w2, WP);
  k_pack3<<<144, TB, 0, stream>>>(w3, WP);
  k_pack4<<<3136, TB, 0, stream>>>(w4, WP);
  k_u1b<<<20384, TB, 0, stream>>>(G, w1, b1);

  ushort_t* cur = S0;
  ushort_t* nxt = S1;
  for (int it = 0; it < NITER; ++it) {
    k_mega<0><<<1963, TB, 0, stream>>>(cur, nxt, G, WP, b2, b3, b4);
    ushort_t* t = cur; cur = nxt; nxt = t;
  }
  // cur == S0 (50 swaps even)

  // post fields P into Pb (hi/lo)
  k_p1<<<2548, TB, 0, stream>>>(Pb, cur, G);
  k_mega<1><<<1326, TB, 0, stream>>>(cur, Pb, G, WP, b2, b3, b4);

  // H partials (transposed, split-K 9) -> Ht hi/lo
  k_hgemm<<<dim3(7, 7, 9), TB, 0, stream>>>(HpT, Pb, cur);
  k_combT<<<(NBn * NBn + TB - 1) / TB, TB, 0, stream>>>(HtH, HtL, HpT);

  // Y = x~ * H via MFMA, then out
  k_xsplit<<<(Bn * NBn + TB - 1) / TB, TB, 0, stream>>>(XH, XL, x, Bn);
  k_ygemm<<<dim3(13, (Bn + 63) / 64), TB, 0, stream>>>(Y, XH, XL, HtH, HtL, Bn);
  k_out<<<(Bn + 3) / 4, TB, 0, stream>>>(out, x, vb, Y, Bn);
}